// Round 3
// baseline (240.406 us; speedup 1.0000x reference)
//
#include <hip/hip_runtime.h>

#define EMBED 1024
#define HEADS 16
#define HDIM 64
#define SQ 1023        // word sequence length
#define SK 1024        // keys = 1 image + 1023 word; also padded Q rows
#define MTOK 4092      // 4*1023 valid token rows
#define MPAD 4096      // padded to 128 multiple

typedef __attribute__((ext_vector_type(8))) short short8;
typedef __attribute__((ext_vector_type(4))) float floatx4;

static __device__ __forceinline__ unsigned short f2bf(float f) {
  union { float f; unsigned u; } v; v.f = f;
  unsigned u = v.u;
  u += 0x7fffu + ((u >> 16) & 1u);
  return (unsigned short)(u >> 16);
}

// async global->LDS, 16B per lane. LDS dest = wave-uniform base + lane*16.
static __device__ __forceinline__ void gld16(const unsigned short* g, unsigned short* l) {
  typedef const __attribute__((address_space(1))) unsigned int guint;
  typedef __attribute__((address_space(3))) unsigned int luint;
  __builtin_amdgcn_global_load_lds((guint*)(const void*)g, (luint*)(void*)l, 16, 0, 0);
}

// ---------------- fused prep kernel ----------------
// regions by blockIdx.x:
//   [0,2048)      cast word -> A bf16 (pad rows zero)
//   [2048,5120)   transpose+cast attn_w (1024x3072) -> WtAttn (3072x1024)
//   [5120,6144)   transpose+cast proj_w (1024x1024) -> WtProj
//   [6144,8192)   img K/V GEMV -> Kb row 0 (row-major), Vt col 0 (transposed)
//   [8192,8208)   zero Q pad row (s=1023)
__global__ __launch_bounds__(256) void k_prep(
    const float* __restrict__ word, const float* __restrict__ attn_w,
    const float* __restrict__ proj_w, const float* __restrict__ img,
    const float* __restrict__ ukw, const float* __restrict__ ukb,
    const float* __restrict__ uvw, const float* __restrict__ uvb,
    unsigned short* __restrict__ A, unsigned short* __restrict__ WtA,
    unsigned short* __restrict__ WtP, unsigned short* __restrict__ Qb,
    unsigned short* __restrict__ Kb, unsigned short* __restrict__ Vt) {
  __shared__ float T[32][33];
  int bx = blockIdx.x, t = threadIdx.x;
  if (bx < 2048) {
    int idx = (bx * 256 + t) * 8;
    int row = idx >> 10;
    short8 v;
    if (row < MTOK) {
      const float4* p = (const float4*)(word + idx);
      float4 a = p[0], b = p[1];
      v[0] = (short)f2bf(a.x); v[1] = (short)f2bf(a.y);
      v[2] = (short)f2bf(a.z); v[3] = (short)f2bf(a.w);
      v[4] = (short)f2bf(b.x); v[5] = (short)f2bf(b.y);
      v[6] = (short)f2bf(b.z); v[7] = (short)f2bf(b.w);
    } else {
#pragma unroll
      for (int i = 0; i < 8; i++) v[i] = 0;
    }
    *(short8*)(A + idx) = v;
  } else if (bx < 6144) {
    const float* W; unsigned short* Wt; int N, n0, k0;
    if (bx < 5120) {
      int r = bx - 2048; W = attn_w; Wt = WtA; N = 3072;
      n0 = (r % 96) * 32; k0 = (r / 96) * 32;
    } else {
      int r = bx - 5120; W = proj_w; Wt = WtP; N = 1024;
      n0 = (r & 31) * 32; k0 = (r >> 5) * 32;
    }
    int tx = t & 31, ty = t >> 5;
#pragma unroll
    for (int i = 0; i < 4; i++) {
      int r = ty + i * 8;
      T[r][tx] = W[(k0 + r) * N + n0 + tx];
    }
    __syncthreads();
#pragma unroll
    for (int i = 0; i < 4; i++) {
      int r = ty + i * 8;
      Wt[(n0 + r) * 1024 + k0 + tx] = f2bf(T[tx][r]);
    }
  } else if (bx < 8192) {
    int wid = (bx - 6144) * 4 + (t >> 6);
    int lane = t & 63;
    int which = wid >> 12;            // 0: k, 1: v
    int bb = (wid >> 10) & 3;
    int n = wid & 1023;
    const float* W = which ? uvw : ukw;
    const float* bias = which ? uvb : ukb;
    const float* x = img + bb * 1024;
    const float* w = W + n * 1024;
    float s = 0.f;
#pragma unroll
    for (int i = 0; i < 16; i++) { int k = i * 64 + lane; s += x[k] * w[k]; }
#pragma unroll
    for (int off = 32; off; off >>= 1) s += __shfl_xor(s, off);
    if (lane == 0) {
      int h = n >> 6, d = n & 63;
      unsigned short val = f2bf(s + bias[n]);
      if (which == 0) Kb[((bb * HEADS + h) * SK + 0) * HDIM + d] = val;
      else            Vt[((bb * HEADS + h) * HDIM + d) * SK + 0] = val;
    }
  } else {
    int i = (bx - 8192) * 256 + t;    // 4096 = 64 bh * 64 d
    int bh = i >> 6, d = i & 63;
    Qb[(bh * SK + (SK - 1)) * HDIM + d] = 0;
  }
}

// ---------------- MFMA GEMM: C[m][n] = sum_k A[m][k]*Bt[n][k] (+bias) ----------------
// 128x128 tile, 4 waves of 64x64, BK=64, global_load_lds 16B staging,
// unpadded LDS with XOR chunk swizzle in K-loop; "+row" chunk rotation in epilogue.
// EPI 0: n-blocks 0-7 -> Qb, 8-15 -> Kb (row-major head-split), 16-23 -> Vt (transposed).
// EPI 1: f32 store to out.
template <int EPI>
__global__ __launch_bounds__(256, 2) void k_gemm(
    const unsigned short* __restrict__ A, const unsigned short* __restrict__ Bt,
    int Kdim, const float* __restrict__ bias,
    unsigned short* __restrict__ Qb, unsigned short* __restrict__ Kb,
    unsigned short* __restrict__ VtOut, float* __restrict__ out) {
  __shared__ __attribute__((aligned(16))) unsigned short Sm[16384];  // As | Bs (32KB)
  unsigned short* As = Sm;           // [128][64], swizzled
  unsigned short* Bs = Sm + 8192;
  int t = threadIdx.x, lane = t & 63, w = t >> 6;
  int quad = lane >> 4, l16 = lane & 15;
  int m0 = blockIdx.y * 128, n0 = blockIdx.x * 128;
  int waveM = (w >> 1) * 64, waveN = (w & 1) * 64;
  int rs = t >> 3, cs = t & 7;

  floatx4 acc[4][4];
#pragma unroll
  for (int i = 0; i < 4; i++)
#pragma unroll
    for (int j = 0; j < 4; j++)
#pragma unroll
      for (int e = 0; e < 4; e++) acc[i][j][e] = 0.f;

  const unsigned short* Ag = A + m0 * Kdim;
  const unsigned short* Bg = Bt + n0 * Kdim;

  for (int k0 = 0; k0 < Kdim; k0 += 64) {
    __syncthreads();
#pragma unroll
    for (int i = 0; i < 4; i++) {
      int r = i * 32 + rs;
      gld16(Ag + r * Kdim + k0 + ((cs ^ (r & 7)) * 8), As + i * 2048 + t * 8);
    }
#pragma unroll
    for (int i = 0; i < 4; i++) {
      int r = i * 32 + rs;
      gld16(Bg + r * Kdim + k0 + ((cs ^ (r & 7)) * 8), Bs + i * 2048 + t * 8);
    }
    __syncthreads();
    short8 af[2][4], bf8[2][4];
#pragma unroll
    for (int kk = 0; kk < 2; kk++) {
#pragma unroll
      for (int mr = 0; mr < 4; mr++) {
        int row = waveM + mr * 16 + l16;
        af[kk][mr] = *(const short8*)(As + row * 64 + (((kk * 4 + quad) ^ (row & 7)) * 8));
      }
#pragma unroll
      for (int nc = 0; nc < 4; nc++) {
        int row = waveN + nc * 16 + l16;
        bf8[kk][nc] = *(const short8*)(Bs + row * 64 + (((kk * 4 + quad) ^ (row & 7)) * 8));
      }
    }
#pragma unroll
    for (int kk = 0; kk < 2; kk++)
#pragma unroll
      for (int mr = 0; mr < 4; mr++)
#pragma unroll
        for (int nc = 0; nc < 4; nc++)
          acc[mr][nc] = __builtin_amdgcn_mfma_f32_16x16x32_bf16(af[kk][mr], bf8[kk][nc], acc[mr][nc], 0, 0, 0);
  }

  float bv[4];
#pragma unroll
  for (int nc = 0; nc < 4; nc++) bv[nc] = bias[n0 + waveN + nc * 16 + l16];

  if (EPI == 0) {
    // repack through LDS (two 64-row passes). Cs chunk slot = ((col>>3)+row)&15.
    unsigned short* Cs = Sm;         // [64][128]
    int which0 = n0 >> 10;           // block-uniform: 0 Q, 1 K, 2 V
    for (int p = 0; p < 2; p++) {
      __syncthreads();
      if ((w >> 1) == p) {
#pragma unroll
        for (int mr = 0; mr < 4; mr++)
#pragma unroll
          for (int nc = 0; nc < 4; nc++)
#pragma unroll
            for (int r = 0; r < 4; r++) {
              int lrow = mr * 16 + quad * 4 + r;
              int lcol = waveN + nc * 16 + l16;
              Cs[lrow * 128 + ((((lcol >> 3) + lrow) & 15) * 8) + (lcol & 7)] =
                  f2bf(acc[mr][nc][r] + bv[nc]);
            }
      }
      __syncthreads();
      if (which0 == 2) {
        // transposed V: lanes = tokens (coalesced 2B stores), loop over cols
        int tok = t & 63;
        int gm = m0 + p * 64 + tok;
        int cb = (t >> 6) * 32;
        bool okm = (gm < MTOK);
        int bb = (unsigned)gm / 1023u;
        int s = gm - bb * 1023;
#pragma unroll
        for (int it = 0; it < 32; it++) {
          int c = cb + it;
          unsigned short val = Cs[tok * 128 + ((((c >> 3) + tok) & 15) * 8) + (c & 7)];
          int e = (n0 + c) & 1023;
          int h = e >> 6, d0 = e & 63;
          if (okm) VtOut[((bb * HEADS + h) * HDIM + d0) * SK + s + 1] = val;
        }
      } else {
        unsigned short* dst = which0 ? Kb : Qb;
        int sofs = which0;           // image occupies key row 0
#pragma unroll
        for (int i = 0; i < 4; i++) {
          int cid = i * 256 + t;
          int lr = cid >> 4, c8 = cid & 15;
          short8 v = *(const short8*)(Cs + lr * 128 + (((c8 + lr) & 15) * 8));
          int gm = m0 + p * 64 + lr;
          if (gm < MTOK) {
            int gn = n0 + c8 * 8;
            int e = gn & 1023;
            int h = e >> 6, d0 = e & 63;
            int bb = (unsigned)gm / 1023u;
            int s = gm - bb * 1023;
            *(short8*)(dst + ((bb * HEADS + h) * SK + s + sofs) * HDIM + d0) = v;
          }
        }
      }
    }
  } else {
#pragma unroll
    for (int nc = 0; nc < 4; nc++) {
      int gn = n0 + waveN + nc * 16 + l16;
#pragma unroll
      for (int mr = 0; mr < 4; mr++) {
#pragma unroll
        for (int r = 0; r < 4; r++) {
          int gm = m0 + waveM + mr * 16 + quad * 4 + r;
          if (gm < MTOK) out[gm * EMBED + gn] = acc[mr][nc][r] + bv[nc];
        }
      }
    }
  }
}

// ---------------- flash attention ----------------
// grid: x = 16 Q-tiles of 64 rows (reversed: heavy first), y = 64 (b*16+h).
// 4 waves, 16 q-rows/wave. Q in registers; K/V^T/P in LDS (48KB -> 3 blocks/CU).
__global__ __launch_bounds__(256, 3) void k_flash(
    const unsigned short* __restrict__ Qb, const unsigned short* __restrict__ Kb,
    const unsigned short* __restrict__ Vtg, const float* __restrict__ am,
    unsigned short* __restrict__ Ao) {
  __shared__ __attribute__((aligned(16))) unsigned short Ks[8192];   // [128][64] xor-swz
  __shared__ __attribute__((aligned(16))) unsigned short Vs[8192];   // [64 d][128 key] xor-swz
  __shared__ __attribute__((aligned(16))) unsigned short Ps[8192];   // 4 waves x [16][128] xor-swz

  int t = threadIdx.x, lane = t & 63, w = t >> 6;
  int quad = lane >> 4, l16 = lane & 15;
  int tq = 15 - (int)blockIdx.x;      // heavy blocks first
  int bh = blockIdx.y;
  int bb = bh >> 4, h = bh & 15;

  // Q fragments in registers (row 1023 is the zeroed pad)
  short8 qf[2];
  {
    int qrow = tq * 64 + w * 16 + l16;
#pragma unroll
    for (int kk = 0; kk < 2; kk++)
      qf[kk] = *(const short8*)(Qb + (bh * SK + qrow) * HDIM + (kk * 4 + quad) * 8);
  }

  const float SCL = 0.18033688011f;     // 0.125 * log2(e)
  const float MASKV = -14426.950408f;   // -10000 * log2(e)
  const float L2E = 1.44269504089f;

  float m_i[4], l_i[4];
  floatx4 acc_o[4];
#pragma unroll
  for (int r = 0; r < 4; r++) { m_i[r] = -1e30f; l_i[r] = 0.f; }
#pragma unroll
  for (int n = 0; n < 4; n++)
#pragma unroll
    for (int e = 0; e < 4; e++) acc_o[n][e] = 0.f;

  unsigned short* Pw = Ps + w * 2048;
  int jmax = min((tq + 1) >> 1, 7);
  for (int j = 0; j <= jmax; j++) {
    __syncthreads();   // prior readers done (drains pending GLDs too)
#pragma unroll
    for (int i = 0; i < 4; i++) {
      int r = i * 32 + (t >> 3), gc = (t & 7) ^ (r & 7);
      gld16(Kb + (bh * SK + j * 128 + r) * HDIM + gc * 8, Ks + i * 2048 + t * 8);
    }
#pragma unroll
    for (int i = 0; i < 4; i++) {
      int d = i * 16 + (t >> 4), gc = (t & 15) ^ (d & 7);
      gld16(Vtg + (bh * HDIM + d) * SK + j * 128 + gc * 8, Vs + i * 2048 + t * 8);
    }
    __syncthreads();

    // dead-wave skip: all this wave's q-rows fully causal-masked in this tile
    bool active_w = (j * 128 <= tq * 64 + w * 16 + 16);
    if (active_w) {
      floatx4 sacc[8];
#pragma unroll
      for (int n = 0; n < 8; n++)
#pragma unroll
        for (int e = 0; e < 4; e++) sacc[n][e] = 0.f;
#pragma unroll
      for (int kk = 0; kk < 2; kk++) {
#pragma unroll
        for (int nc = 0; nc < 8; nc++) {
          int krow = nc * 16 + l16;
          short8 b = *(const short8*)(Ks + krow * 64 + (((kk * 4 + quad) ^ (krow & 7)) * 8));
          sacc[nc] = __builtin_amdgcn_mfma_f32_16x16x32_bf16(qf[kk], b, sacc[nc], 0, 0, 0);
        }
      }

      // exp2-domain: scale scores by log2(e) throughout
      int qbase = tq * 64 + w * 16 + quad * 4;
      float sval[8][4], tmax[4];
      bool deadnc[8];
#pragma unroll
      for (int r = 0; r < 4; r++) tmax[r] = -1e30f;
#pragma unroll
      for (int nc = 0; nc < 8; nc++) {
        deadnc[nc] = (j * 128 + nc * 16) > (tq * 64 + w * 16 + 16);  // wave-uniform
        if (deadnc[nc]) {
#pragma unroll
          for (int r = 0; r < 4; r++) sval[nc][r] = 0.f;   // P = 0
        } else {
          int kg = j * 128 + nc * 16 + l16;
          float amv = ((kg >= 1) ? am[bb * SQ + kg - 1] : 0.f) * L2E;
#pragma unroll
          for (int r = 0; r < 4; r++) {
            float sc = sacc[nc][r] * SCL;
            if (kg > qbase + r + 1) sc = MASKV;
            sc += amv;
            sval[nc][r] = sc;
            tmax[r] = fmaxf(tmax[r], sc);
          }
        }
      }
#pragma unroll
      for (int off = 1; off < 16; off <<= 1)
#pragma unroll
        for (int r = 0; r < 4; r++) tmax[r] = fmaxf(tmax[r], __shfl_xor(tmax[r], off));

      float alpha[4];
#pragma unroll
      for (int r = 0; r < 4; r++) {
        float mn = fmaxf(m_i[r], tmax[r]);
        alpha[r] = __builtin_amdgcn_exp2f(m_i[r] - mn);
        m_i[r] = mn;
      }
      float rsum[4] = {0.f, 0.f, 0.f, 0.f};
#pragma unroll
      for (int nc = 0; nc < 8; nc++) {
        if (!deadnc[nc]) {
#pragma unroll
          for (int r = 0; r < 4; r++) {
            float p = __builtin_amdgcn_exp2f(sval[nc][r] - m_i[r]);
            sval[nc][r] = p;
            rsum[r] += p;
          }
        }
      }
#pragma unroll
      for (int off = 1; off < 16; off <<= 1)
#pragma unroll
        for (int r = 0; r < 4; r++) rsum[r] += __shfl_xor(rsum[r], off);
#pragma unroll
      for (int r = 0; r < 4; r++) l_i[r] = l_i[r] * alpha[r] + rsum[r];
#pragma unroll
      for (int n = 0; n < 4; n++)
#pragma unroll
        for (int e = 0; e < 4; e++) acc_o[n][e] *= alpha[e];

      // P: C-layout -> wave-private LDS, truncating bf16 pack (p in [0,1])
#pragma unroll
      for (int nc = 0; nc < 8; nc++)
#pragma unroll
        for (int r = 0; r < 4; r++) {
          int row = quad * 4 + r;
          union { float f; unsigned u; } cv; cv.f = sval[nc][r];
          Pw[row * 128 + (((nc * 2 + (l16 >> 3)) ^ (row & 7)) * 8) + (l16 & 7)] =
              (unsigned short)(cv.u >> 16);
        }

      // O += P V  (Vs holds V^T tile: rows = d, cols = key)
#pragma unroll
      for (int kk2 = 0; kk2 < 4; kk2++) {
        short8 a = *(const short8*)(Pw + l16 * 128 + (((kk2 * 4 + quad) ^ (l16 & 7)) * 8));
#pragma unroll
        for (int n = 0; n < 4; n++) {
          int vrow = n * 16 + l16;
          short8 b = *(const short8*)(Vs + vrow * 128 + (((kk2 * 4 + quad) ^ (vrow & 7)) * 8));
          acc_o[n] = __builtin_amdgcn_mfma_f32_16x16x32_bf16(a, b, acc_o[n], 0, 0, 0);
        }
      }
    }
  }

  // normalize, repack via LDS (Os overlays Ps), vectorized store
  float inv[4];
#pragma unroll
  for (int r = 0; r < 4; r++) inv[r] = 1.f / l_i[r];
  unsigned short* Os = Ps;   // [64][64], "+row" chunk rotation
  __syncthreads();
#pragma unroll
  for (int n = 0; n < 4; n++)
#pragma unroll
    for (int r = 0; r < 4; r++) {
      int row = w * 16 + quad * 4 + r, col = n * 16 + l16;
      Os[row * 64 + ((((col >> 3) + row) & 7) * 8) + (col & 7)] = f2bf(acc_o[n][r] * inv[r]);
    }
  __syncthreads();
#pragma unroll
  for (int i = 0; i < 2; i++) {
    int cid = i * 256 + t, r = cid >> 3, c8 = cid & 7;
    int q = tq * 64 + r;
    if (q < SQ) {
      short8 v = *(const short8*)(Os + r * 64 + (((c8 + r) & 7) * 8));
      *(short8*)(Ao + (bb * SQ + q) * EMBED + h * HDIM + c8 * 8) = v;
    }
  }
}

// ---------------- launch ----------------
extern "C" void kernel_launch(void* const* d_in, const int* in_sizes, int n_in,
                              void* d_out, int out_size, void* d_ws, size_t ws_size,
                              hipStream_t stream) {
  const float* word   = (const float*)d_in[0];
  const float* img    = (const float*)d_in[1];
  const float* amask  = (const float*)d_in[2];
  const float* attn_w = (const float*)d_in[3];
  const float* attn_b = (const float*)d_in[4];
  const float* proj_w = (const float*)d_in[5];
  const float* proj_b = (const float*)d_in[6];
  const float* ukw    = (const float*)d_in[7];
  const float* ukb    = (const float*)d_in[8];
  const float* uvw    = (const float*)d_in[9];
  const float* uvb    = (const float*)d_in[10];
  float* out = (float*)d_out;

  char* ws = (char*)d_ws;
  unsigned short* Aw     = (unsigned short*)(ws);                 // [0,8MB) A / later Ao
  unsigned short* WtAttn = (unsigned short*)(ws + 8388608);       // [8,14MB)
  unsigned short* WtProj = (unsigned short*)(ws + 14680064);      // [14,16MB)
  unsigned short* Qb     = (unsigned short*)(ws + 16777216);      // [16,24MB)
  unsigned short* Kb     = (unsigned short*)(ws + 25165824);      // [24,32MB)
  unsigned short* Vtg    = (unsigned short*)(ws + 33554432);      // [32,40MB) V^T (bh,d,key)
  unsigned short* Ao     = Aw;  // reuse: A dead after QKV GEMM

  k_prep<<<8208, 256, 0, stream>>>(word, attn_w, proj_w, img, ukw, ukb, uvw, uvb,
                                   Aw, WtAttn, WtProj, Qb, Kb, Vtg);
  k_gemm<0><<<dim3(24, 32), 256, 0, stream>>>(Aw, WtAttn, 1024, attn_b, Qb, Kb, Vtg, nullptr);
  k_flash<<<dim3(16, 64), 256, 0, stream>>>(Qb, Kb, Vtg, amask, Ao);
  k_gemm<1><<<dim3(8, 32), 256, 0, stream>>>(Ao, WtProj, 1024, proj_b, nullptr, nullptr, nullptr, out);
}